// Round 4
// baseline (3061.609 us; speedup 1.0000x reference)
//
#include <hip/hip_runtime.h>
#include <cstdint>

// ---------------------------------------------------------------------------
// ChartParser: span scores (3 fp32 GEMMs) + per-batch CKY DP + backtrack.
// B=64, S=256, D=H=1024. Output: int32 [2][B][S] (lefts then rights).
// Round 4: (a) CKY i-quad vectorization: ds_read_b128 left + ds_read2_b32
// right -> 3 LDS instrs per 4 (i,m) pairs (was 8); diagonals padded to 4
// floats, off(m) = 256m - 8a(a-1) - 4ab closed form. (b) big GEMMs use
// 256x128 tile, 16x8 microtile (FLOP/LDS-byte 2.0 -> 2.67).
// ---------------------------------------------------------------------------

#define Bb 64
#define Ss 256
#define Dd 1024
#define Hh 1024

// ---------------------------------------------------------------------------
// Repack Wbil [1025,1025] into core [1024,1024] + last row + last col + corner
// ---------------------------------------------------------------------------
__global__ __launch_bounds__(256) void repack_kernel(
    const float* __restrict__ Wbil, float* __restrict__ Wcore,
    float* __restrict__ brow, float* __restrict__ bcol,
    float* __restrict__ corner) {
  int idx = blockIdx.x * 256 + threadIdx.x;  // 0 .. 1048575
  int h = idx >> 10, g = idx & 1023;
  Wcore[idx] = Wbil[h * 1025 + g];
  if (h == 0) brow[g] = Wbil[1024 * 1025 + g];
  if (g == 0) bcol[h] = Wbil[h * 1025 + 1024];
  if (idx == 0) corner[0] = Wbil[1024 * 1025 + 1024];
}

// ---------------------------------------------------------------------------
// Big fp32 GEMM (NN): C = act(A[M,K] * B[K,N] + bias[n]), 256x128 tile,
// 256 threads, 16x8 microtile, double-buffered LDS.
// grid = (N/128, M/256).
// ---------------------------------------------------------------------------
template <bool LEAKY>
__global__ __launch_bounds__(256) void gemm256_kernel(
    const float* __restrict__ A, int lda, const float* __restrict__ B, int ldb,
    float* __restrict__ C, int ldc, const float* __restrict__ bias, int K) {
  const int m0 = blockIdx.y * 256;
  const int n0 = blockIdx.x * 128;
  __shared__ __align__(16) float As[2][8][256];
  __shared__ __align__(16) float Bs[2][8][128];
  const int t = threadIdx.x;
  const int tx = t & 15, ty = t >> 4;
  const int ar = t >> 1, ak = (t & 1) * 4;     // A staging: rows ar, ar+128
  const int bk = t >> 5, bn = (t & 31) * 4;    // B staging

  float acc[16][8];
#pragma unroll
  for (int i = 0; i < 16; ++i)
#pragma unroll
    for (int j = 0; j < 8; ++j) acc[i][j] = 0.f;

  // prologue: stage k0=0 into buffer 0
  {
    float4 a0 = *(const float4*)(A + (long long)(m0 + ar) * lda + ak);
    float4 a1 = *(const float4*)(A + (long long)(m0 + ar + 128) * lda + ak);
    float4 bv = *(const float4*)(B + (long long)bk * ldb + (n0 + bn));
    As[0][ak + 0][ar] = a0.x;
    As[0][ak + 1][ar] = a0.y;
    As[0][ak + 2][ar] = a0.z;
    As[0][ak + 3][ar] = a0.w;
    As[0][ak + 0][ar + 128] = a1.x;
    As[0][ak + 1][ar + 128] = a1.y;
    As[0][ak + 2][ar + 128] = a1.z;
    As[0][ak + 3][ar + 128] = a1.w;
    *(float4*)&Bs[0][bk][bn] = bv;
  }
  __syncthreads();

  int cur = 0;
  for (int k0 = 0; k0 < K; k0 += 8) {
    float4 pa0, pa1, pbv;
    const bool more = (k0 + 8) < K;
    if (more) {
      pa0 = *(const float4*)(A + (long long)(m0 + ar) * lda + (k0 + 8 + ak));
      pa1 = *(const float4*)(A + (long long)(m0 + ar + 128) * lda +
                             (k0 + 8 + ak));
      pbv = *(const float4*)(B + (long long)(k0 + 8 + bk) * ldb + (n0 + bn));
    }
#pragma unroll
    for (int k = 0; k < 8; ++k) {
      float4 a0 = *(const float4*)&As[cur][k][ty * 4];
      float4 a1 = *(const float4*)&As[cur][k][64 + ty * 4];
      float4 a2 = *(const float4*)&As[cur][k][128 + ty * 4];
      float4 a3 = *(const float4*)&As[cur][k][192 + ty * 4];
      float4 b0 = *(const float4*)&Bs[cur][k][tx * 4];
      float4 b1 = *(const float4*)&Bs[cur][k][64 + tx * 4];
      float a[16] = {a0.x, a0.y, a0.z, a0.w, a1.x, a1.y, a1.z, a1.w,
                     a2.x, a2.y, a2.z, a2.w, a3.x, a3.y, a3.z, a3.w};
      float bb[8] = {b0.x, b0.y, b0.z, b0.w, b1.x, b1.y, b1.z, b1.w};
#pragma unroll
      for (int i = 0; i < 16; ++i)
#pragma unroll
        for (int j = 0; j < 8; ++j) acc[i][j] = fmaf(a[i], bb[j], acc[i][j]);
    }
    if (more) {
      const int nxt = cur ^ 1;
      As[nxt][ak + 0][ar] = pa0.x;
      As[nxt][ak + 1][ar] = pa0.y;
      As[nxt][ak + 2][ar] = pa0.z;
      As[nxt][ak + 3][ar] = pa0.w;
      As[nxt][ak + 0][ar + 128] = pa1.x;
      As[nxt][ak + 1][ar + 128] = pa1.y;
      As[nxt][ak + 2][ar + 128] = pa1.z;
      As[nxt][ak + 3][ar + 128] = pa1.w;
      *(float4*)&Bs[nxt][bk][bn] = pbv;
    }
    __syncthreads();
    cur ^= 1;
  }

#pragma unroll
  for (int h = 0; h < 4; ++h) {
#pragma unroll
    for (int ii = 0; ii < 4; ++ii) {
      int row = m0 + h * 64 + ty * 4 + ii;
#pragma unroll
      for (int jh = 0; jh < 2; ++jh) {
        int col = n0 + jh * 64 + tx * 4;
        float vv[4];
#pragma unroll
        for (int jj = 0; jj < 4; ++jj) {
          float x = acc[h * 4 + ii][jh * 4 + jj] + bias[col + jj];
          if (LEAKY) x = (x > 0.f) ? x : 0.1f * x;
          vv[jj] = x;
        }
        *(float4*)(C + (long long)row * ldc + col) =
            make_float4(vv[0], vv[1], vv[2], vv[3]);
      }
    }
  }
}

// ---------------------------------------------------------------------------
// Batched NT GEMM for scores (128x128 tile, 8x8 microtile) — unchanged.
// C = A[M,K] * B^T + rowAdd[m] + scal. grid = (N/128, M/128, batch).
// ---------------------------------------------------------------------------
__global__ __launch_bounds__(256) void gemmnt_kernel(
    const float* __restrict__ A, int lda, long long sA,
    const float* __restrict__ B, int ldb, long long sB,
    float* __restrict__ C, int ldc, long long sC,
    const float* __restrict__ rowAdd, long long sRow,
    const float* __restrict__ scal, int K) {
  const int bz = blockIdx.z;
  A += (long long)bz * sA;
  B += (long long)bz * sB;
  C += (long long)bz * sC;
  const int m0 = blockIdx.y * 128;
  const int n0 = blockIdx.x * 128;
  __shared__ __align__(16) float As[2][8][128];
  __shared__ __align__(16) float Bs[2][8][128];
  const int t = threadIdx.x;
  const int tx = t & 15, ty = t >> 4;
  const int arow = t >> 1, ak = (t & 1) * 4;
  const int bn_t = t >> 1, bk_t = (t & 1) * 4;

  float acc[8][8];
#pragma unroll
  for (int i = 0; i < 8; ++i)
#pragma unroll
    for (int j = 0; j < 8; ++j) acc[i][j] = 0.f;

  {
    float4 av = *(const float4*)(A + (long long)(m0 + arow) * lda + ak);
    float4 bv = *(const float4*)(B + (long long)(n0 + bn_t) * ldb + bk_t);
    As[0][ak + 0][arow] = av.x;
    As[0][ak + 1][arow] = av.y;
    As[0][ak + 2][arow] = av.z;
    As[0][ak + 3][arow] = av.w;
    Bs[0][bk_t + 0][bn_t] = bv.x;
    Bs[0][bk_t + 1][bn_t] = bv.y;
    Bs[0][bk_t + 2][bn_t] = bv.z;
    Bs[0][bk_t + 3][bn_t] = bv.w;
  }
  __syncthreads();

  int cur = 0;
  for (int k0 = 0; k0 < K; k0 += 8) {
    float4 av, bv;
    const bool more = (k0 + 8) < K;
    if (more) {
      av = *(const float4*)(A + (long long)(m0 + arow) * lda + (k0 + 8 + ak));
      bv = *(const float4*)(B + (long long)(n0 + bn_t) * ldb + (k0 + 8 + bk_t));
    }
#pragma unroll
    for (int k = 0; k < 8; ++k) {
      float4 a0 = *(const float4*)&As[cur][k][ty * 4];
      float4 a1 = *(const float4*)&As[cur][k][64 + ty * 4];
      float4 b0 = *(const float4*)&Bs[cur][k][tx * 4];
      float4 b1 = *(const float4*)&Bs[cur][k][64 + tx * 4];
      float a[8] = {a0.x, a0.y, a0.z, a0.w, a1.x, a1.y, a1.z, a1.w};
      float bb[8] = {b0.x, b0.y, b0.z, b0.w, b1.x, b1.y, b1.z, b1.w};
#pragma unroll
      for (int i = 0; i < 8; ++i)
#pragma unroll
        for (int j = 0; j < 8; ++j) acc[i][j] = fmaf(a[i], bb[j], acc[i][j]);
    }
    if (more) {
      const int nxt = cur ^ 1;
      As[nxt][ak + 0][arow] = av.x;
      As[nxt][ak + 1][arow] = av.y;
      As[nxt][ak + 2][arow] = av.z;
      As[nxt][ak + 3][arow] = av.w;
      Bs[nxt][bk_t + 0][bn_t] = bv.x;
      Bs[nxt][bk_t + 1][bn_t] = bv.y;
      Bs[nxt][bk_t + 2][bn_t] = bv.z;
      Bs[nxt][bk_t + 3][bn_t] = bv.w;
    }
    __syncthreads();
    cur ^= 1;
  }

  const float sc_add = scal[0];
#pragma unroll
  for (int ih = 0; ih < 2; ++ih) {
#pragma unroll
    for (int ii = 0; ii < 4; ++ii) {
      int row = m0 + ih * 64 + ty * 4 + ii;
      float radd = sc_add + rowAdd[(long long)bz * sRow + row];
#pragma unroll
      for (int jh = 0; jh < 2; ++jh) {
        int col = n0 + jh * 64 + tx * 4;
        float4 v = make_float4(acc[ih * 4 + ii][jh * 4 + 0] + radd,
                               acc[ih * 4 + ii][jh * 4 + 1] + radd,
                               acc[ih * 4 + ii][jh * 4 + 2] + radd,
                               acc[ih * 4 + ii][jh * 4 + 3] + radd);
        *(float4*)(C + (long long)row * ldc + col) = v;
      }
    }
  }
}

// ---------------------------------------------------------------------------
// tmpb[i] = dot(lefts[i,:], Wbil[0:H, H]) + Wbil[H,H].  One wave per row.
// ---------------------------------------------------------------------------
__global__ __launch_bounds__(64) void colvec_kernel(
    const float* __restrict__ lefts, const float* __restrict__ bcol,
    const float* __restrict__ corner, float* __restrict__ tmpb) {
  int row = blockIdx.x;
  int lane = threadIdx.x;
  const float* a = lefts + (long long)row * Hh;
  float s = 0.f;
#pragma unroll
  for (int h = lane; h < Hh; h += 64) s = fmaf(a[h], bcol[h], s);
#pragma unroll
  for (int off = 32; off > 0; off >>= 1) s += __shfl_down(s, off, 64);
  if (lane == 0) tmpb[row] = s + corner[0];
}

// ---------------------------------------------------------------------------
// CKY + backtrack. One block per batch, 1024 threads. Chart in LDS, packed
// diag-major with each diagonal padded to a 4-float boundary:
//   align4(256-k) = 256 - (k & ~3)  ->  off(m) = 256m - 8a(a-1) - 4ab,
//   a = m>>2, b = m&3.  Total 33280 floats (133 KB).
// Each thread handles an i-QUAD (4 consecutive spans): left operand is one
// aligned ds_read_b128 (D[m][qi..qi+3]); right operand D[kr][qi+m+1..+3] is
// 4 adjacent b32 reads (-> 2x ds_read2_b32). Adaptive m-groups G in
// {16,32,64} by diagonal length; ascending-(g,m) strict-> combine preserves
// jnp.argmax first-max semantics.
// ---------------------------------------------------------------------------
__global__ __launch_bounds__(1024) void cky_kernel(
    const float* __restrict__ scores,  // [64][256][256]
    uint8_t* __restrict__ Sws,         // [64][33280] padded triangular
    int* __restrict__ out)             // [2][64][256] int32
{
  const int b = blockIdx.x;
  const int t = threadIdx.x;
  const int n = Ss;
  const float* sc = scores + (long long)b * n * n;
  uint8_t* SP = Sws + (long long)b * 33280;

  __shared__ __align__(16) float Dch[33296];  // padded chart + guard
  __shared__ __align__(16) float pv[4096];    // partials: [G][4<<lgQ]
  __shared__ uint8_t pmv[4096];
  __shared__ int stk[256];

  if (t < n) {
    out[b * n + t] = 0;  // slot n-1 must stay 0 (torch.zeros semantics)
    out[Bb * n + b * n + t] = 0;
    Dch[t] = 0.f;  // width-0 diagonal (off(0)=0, len 256)
  }
  __syncthreads();

  int offw = 256;  // off(1)
  for (int w = 1; w < n; ++w) {
    const int nv = n - w;
    const int NQ = (nv + 3) >> 2;                       // i-quads needed
    const int lgQ = (NQ > 32) ? 6 : (NQ > 16) ? 5 : 4;  // quad slots = 1<<lgQ
    const int G = 1024 >> lgQ;                          // m-groups (16/32/64)
    const int u = t & ((1 << lgQ) - 1);
    const int g = t >> lgQ;
    const int qi = u * 4;

    float scv = 0.f;
    if (t < nv) scv = sc[t * (n + 1) + w];

    const int wG = (w + G - 1) >> (10 - lgQ);  // ceil(w/G)
    const int ml = g * wG;
    const int mh = (w < ml + wG) ? w : (ml + wG);

    float bv0 = -3.0e38f, bv1 = -3.0e38f, bv2 = -3.0e38f, bv3 = -3.0e38f;
    int bm0 = 0, bm1 = 0, bm2 = 0, bm3 = 0;
    if (qi < nv && ml < mh) {
      int a2 = ml >> 2;
      int al = (ml << 8) - 8 * a2 * (a2 - 1) - 4 * a2 * (ml & 3) + qi;
      int kr = w - 1 - ml;
      int a3 = kr >> 2;
      int ar = (kr << 8) - 8 * a3 * (a3 - 1) - 4 * a3 * (kr & 3) + qi + ml + 1;
#pragma unroll 2
      for (int m = ml; m < mh; ++m) {
        float4 lv = *(const float4*)(Dch + al);
        float r0 = Dch[ar], r1 = Dch[ar + 1], r2 = Dch[ar + 2],
              r3 = Dch[ar + 3];
        float c0 = lv.x + r0, c1 = lv.y + r1, c2 = lv.z + r2, c3 = lv.w + r3;
        if (c0 > bv0) { bv0 = c0; bm0 = m; }  // strict > = first max
        if (c1 > bv1) { bv1 = c1; bm1 = m; }
        if (c2 > bv2) { bv2 = c2; bm2 = m; }
        if (c3 > bv3) { bv3 = c3; bm3 = m; }
        al += 256 - (m & ~3);
        ar += 1 - 256 + ((kr - 1) & ~3);
        --kr;
      }
    }
    const int base = (g << (lgQ + 2)) + qi;
    *(float4*)(pv + base) = make_float4(bv0, bv1, bv2, bv3);
    *(uchar4*)(pmv + base) = make_uchar4((unsigned char)bm0, (unsigned char)bm1,
                                         (unsigned char)bm2, (unsigned char)bm3);
    __syncthreads();

    if (t < nv) {
      float bb = pv[t];  // g2=0 row starts at 0
      int bm = pmv[t];
#pragma unroll 4
      for (int g2 = 1; g2 < G; ++g2) {
        const int idx = (g2 << (lgQ + 2)) + t;
        float v = pv[idx];
        if (v > bb) {  // ascending g + strict > = first max overall
          bb = v;
          bm = pmv[idx];
        }
      }
      Dch[offw + t] = scv + bb;
      SP[offw + t] = (uint8_t)bm;
    }
    __syncthreads();
    offw += (nv + 3) & ~3;
  }

  // ---- backtrack: copy SP into the dead chart's LDS, then serial chase ----
  uint8_t* spl = (uint8_t*)Dch;  // chart is dead; 33280 B fits
  for (int idx = t; idx < 33280; idx += 1024) spl[idx] = SP[idx];
  __syncthreads();
  if (t == 0) {
    int top = 0;
    stk[top++] = (0 << 16) | (n - 1);
    int cnt = 0;
    for (int step = 0; step < n - 1; ++step) {
      if (top > 0) {
        int ij = stk[--top];
        int ii = ij >> 16, jj = ij & 0xffff;
        out[b * n + cnt] = ii;
        out[Bb * n + b * n + cnt] = jj;
        ++cnt;
        int k = jj - ii;
        int a4 = k >> 2;
        int offk = (k << 8) - 8 * a4 * (a4 - 1) - 4 * a4 * (k & 3);
        int s = ii + (int)spl[offk + ii];
        stk[top] = (ii << 16) | s;
        if (s > ii) ++top;
        stk[top] = ((s + 1) << 16) | jj;
        if (jj > s + 1) ++top;
      }
    }
  }
}

// ---------------------------------------------------------------------------
// Launch
// ---------------------------------------------------------------------------
extern "C" void kernel_launch(void* const* d_in, const int* in_sizes, int n_in,
                              void* d_out, int out_size, void* d_ws,
                              size_t ws_size, hipStream_t stream) {
  const float* X = (const float*)d_in[0];     // [64,256,1024]
  const float* Wl = (const float*)d_in[2];    // [1024,1024]
  const float* bl = (const float*)d_in[3];    // [1024]
  const float* Wr = (const float*)d_in[4];
  const float* br = (const float*)d_in[5];
  const float* Wbil = (const float*)d_in[6];  // [1025,1025]
  const float* bbil = (const float*)d_in[7];  // scalar
  int* out = (int*)d_out;

  // workspace layout (floats)
  float* ws = (float*)d_ws;
  const long long NROWS = (long long)Bb * Ss;      // 16384
  float* lefts = ws;                               // 16384x1024
  float* rights = lefts + NROWS * Hh;              // 16384x1024
  float* tmpA = rights + NROWS * Hh;               // 16384x1024
  float* scoresP = tmpA + NROWS * Hh;              // 64x256x256
  float* tmpb = scoresP + (long long)Bb * Ss * Ss; // 16384
  float* Wcore = tmpb + NROWS;                     // 1024x1024
  float* browp = Wcore + (long long)Dd * Hh;       // 1024
  float* bcolp = browp + Hh;                       // 1024
  float* cornerp = bcolp + Hh;                     // 1
  uint8_t* SPp = (uint8_t*)(cornerp + 3);          // 64x33280 u8 (4B aligned)

  repack_kernel<<<dim3(4096), dim3(256), 0, stream>>>(Wbil, Wcore, browp,
                                                      bcolp, cornerp);

  dim3 g1(Hh / 128, NROWS / 256);  // (8,64)
  gemm256_kernel<true><<<g1, 256, 0, stream>>>(X, Dd, Wl, Hh, lefts, Hh, bl,
                                               Dd);
  gemm256_kernel<true><<<g1, 256, 0, stream>>>(X, Dd, Wr, Hh, rights, Hh, br,
                                               Dd);

  colvec_kernel<<<dim3(NROWS), dim3(64), 0, stream>>>(lefts, bcolp, cornerp,
                                                      tmpb);

  gemm256_kernel<false><<<g1, 256, 0, stream>>>(lefts, Hh, Wcore, Hh, tmpA, Hh,
                                                browp, Hh);

  dim3 g3(Ss / 128, Ss / 128, Bb);  // (2,2,64)
  gemmnt_kernel<<<g3, 256, 0, stream>>>(
      tmpA, Hh, (long long)Ss * Hh, rights, Hh, (long long)Ss * Hh, scoresP,
      Ss, (long long)Ss * Ss, tmpb, (long long)Ss, bbil, Hh);

  cky_kernel<<<dim3(Bb), dim3(1024), 0, stream>>>(scoresP, SPp, out);
}

// Round 5
// 1634.307 us; speedup vs baseline: 1.8733x; 1.8733x over previous
//
#include <hip/hip_runtime.h>
#include <cstdint>

// ---------------------------------------------------------------------------
// ChartParser: span scores + per-batch CKY DP + backtrack.
// B=64, S=256, D=H=1024. Output: int32 [2][B][S] (lefts then rights).
// Round 5: big GEMMs on MFMA via exact bf16x3 limb split (8 products,
// fp32-accurate); weights pre-split+transposed to bf16 [N,K]; A split
// in-kernel during staging. CKY reverted to the round-3 kernel (known-good).
// ---------------------------------------------------------------------------

#define Bb 64
#define Ss 256
#define Dd 1024
#define Hh 1024

typedef __attribute__((ext_vector_type(8))) short bf16x8;
typedef __attribute__((ext_vector_type(4))) float f32x4;

__device__ __forceinline__ unsigned short bf16_rne(float x) {
  unsigned u = __float_as_uint(x);
  unsigned r = (u + 0x7FFFu + ((u >> 16) & 1u)) >> 16;
  return (unsigned short)r;
}
__device__ __forceinline__ float bf16_to_f(unsigned short h) {
  return __uint_as_float(((unsigned)h) << 16);
}

// ---------------------------------------------------------------------------
// Weight split+transpose: W fp32 [K rows, ld ldw] -> O (3 x 1024x1024 bf16,
// layout [n][k], limbs h|m|l at +0, +1M, +2M elements). x = h+m+l exact to
// 2^-24 rel. Reads are strided (L2 absorbs, W is 4MB); writes coalesced.
// ---------------------------------------------------------------------------
__global__ __launch_bounds__(256) void splitw_kernel(
    const float* __restrict__ W, int ldw, unsigned short* __restrict__ O) {
  int idx = blockIdx.x * 256 + threadIdx.x;  // n*1024 + k
  int n = idx >> 10, k = idx & 1023;
  float x = W[(long long)k * ldw + n];
  unsigned short h = bf16_rne(x);
  float r = x - bf16_to_f(h);
  unsigned short m = bf16_rne(r);
  float r2 = r - bf16_to_f(m);
  unsigned short l = bf16_rne(r2);
  O[idx] = h;
  O[1048576 + idx] = m;
  O[2097152 + idx] = l;
}

// Extract Wbil's bias row / col / corner.
__global__ __launch_bounds__(256) void bilvec_kernel(
    const float* __restrict__ Wbil, float* __restrict__ brow,
    float* __restrict__ bcol, float* __restrict__ corner) {
  int i = blockIdx.x * 256 + threadIdx.x;  // 0..1023
  brow[i] = Wbil[1024 * 1025 + i];
  bcol[i] = Wbil[i * 1025 + 1024];
  if (i == 0) corner[0] = Wbil[1024 * 1025 + 1024];
}

// ---------------------------------------------------------------------------
// MFMA GEMM (NN): C[M,1024] = act(A[M,1024]_fp32 * B[1024,1024] + bias[n]).
// A is split in-kernel into bf16 limbs (h,m,l) during LDS staging; B comes
// pre-split (+transposed [n][k]) in Bsp. Exact-fp32 emulation: 8 limb
// products (skip l*l only, ~2^-32). Tile 128x128, BK=32, 256 threads =
// 4 waves, wave-tile 64x64 = 4x4 frags of v_mfma_f32_16x16x32_bf16.
// LDS 48KB (3 blocks/CU): 6 tiles of 128 rows x 64B, 16B-chunk XOR swizzle
// phi(r)=((r>>1)^(r>>3))&3 -> frag reads 2-way (free).
// Frag layouts (verified, cdna_hip_programming.md §3):
//   A: m=lane&15, k=quad*8+j ; B: n=lane&15, k=quad*8+j ;
//   C/D: col=lane&15, row=quad*4+reg.
// ---------------------------------------------------------------------------
__device__ __forceinline__ void pack8(char* dst, const unsigned short* v) {
  uint4 u;
  u.x = (unsigned)v[0] | ((unsigned)v[1] << 16);
  u.y = (unsigned)v[2] | ((unsigned)v[3] << 16);
  u.z = (unsigned)v[4] | ((unsigned)v[5] << 16);
  u.w = (unsigned)v[6] | ((unsigned)v[7] << 16);
  *(uint4*)dst = u;
}

template <bool LEAKY>
__global__ __launch_bounds__(256, 3) void gemm_mfma_kernel(
    const float* __restrict__ A, const unsigned short* __restrict__ Bsp,
    float* __restrict__ C, const float* __restrict__ bias) {
  const int m0 = blockIdx.y * 128;
  const int n0 = blockIdx.x * 128;
  __shared__ char lds[49152];  // A limbs at 0,8192,16384; B at 24576+...
  const int t = threadIdx.x;
  const int L = t & 63, w = t >> 6, q = L >> 4, l15 = L & 15;

  // A staging: thread -> (row ar, k-half ah) : 16 fp32
  const int ar = t >> 1, ah = t & 1;
  const float* aptr = A + (long long)(m0 + ar) * 1024 + ah * 16;
  const int phiA = ((ar >> 1) ^ (ar >> 3)) & 3;
  const int wa0 = ar * 64 + (((2 * ah + 0) ^ phiA) << 4);
  const int wa1 = ar * 64 + (((2 * ah + 1) ^ phiA) << 4);

  // frag read offsets (static across stages)
  int offA0[4], offB0[4];
#pragma unroll
  for (int f = 0; f < 4; ++f) {
    int rowa = ((w & 1) << 6) + (f << 4) + l15;
    offA0[f] = rowa * 64 + ((q ^ (((rowa >> 1) ^ (rowa >> 3)) & 3)) << 4);
    int rowb = ((w >> 1) << 6) + (f << 4) + l15;
    offB0[f] =
        24576 + rowb * 64 + ((q ^ (((rowb >> 1) ^ (rowb >> 3)) & 3)) << 4);
  }

  f32x4 acc[4][4];
#pragma unroll
  for (int i = 0; i < 4; ++i)
#pragma unroll
    for (int j = 0; j < 4; ++j) acc[i][j] = (f32x4){0.f, 0.f, 0.f, 0.f};

  for (int k0 = 0; k0 < 1024; k0 += 32) {
    // ---- B staging: 6 x 16B per thread (pre-split bf16, swizzled dest) ----
#pragma unroll
    for (int j = 0; j < 6; ++j) {
      int fc = t + (j << 8);  // 0..1535
      int s = fc >> 9, r = (fc >> 2) & 127, sc = fc & 3;
      const unsigned short* bs = Bsp + s * 1048576;
      uint4 bv = *(const uint4*)(bs + (long long)(n0 + r) * 1024 + k0 + (sc << 3));
      int phi = ((r >> 1) ^ (r >> 3)) & 3;
      *(uint4*)&lds[24576 + s * 8192 + r * 64 + ((sc ^ phi) << 4)] = bv;
    }
    // ---- A staging: 16 fp32 -> 3 x 16 bf16 limbs ----
    {
      float4 a0 = *(const float4*)(aptr + k0);
      float4 a1 = *(const float4*)(aptr + k0 + 4);
      float4 a2 = *(const float4*)(aptr + k0 + 8);
      float4 a3 = *(const float4*)(aptr + k0 + 12);
      float xs[16] = {a0.x, a0.y, a0.z, a0.w, a1.x, a1.y, a1.z, a1.w,
                      a2.x, a2.y, a2.z, a2.w, a3.x, a3.y, a3.z, a3.w};
      unsigned short hs[16], ms[16], ls[16];
#pragma unroll
      for (int i = 0; i < 16; ++i) {
        hs[i] = bf16_rne(xs[i]);
        float r = xs[i] - bf16_to_f(hs[i]);
        ms[i] = bf16_rne(r);
        float r2 = r - bf16_to_f(ms[i]);
        ls[i] = bf16_rne(r2);
      }
      pack8(&lds[wa0], hs);
      pack8(&lds[wa1], hs + 8);
      pack8(&lds[8192 + wa0], ms);
      pack8(&lds[8192 + wa1], ms + 8);
      pack8(&lds[16384 + wa0], ls);
      pack8(&lds[16384 + wa1], ls + 8);
    }
    __syncthreads();
    // ---- compute: 8 limb products x 4x4 frags ----
    bf16x8 af[3][4];
#pragma unroll
    for (int s = 0; s < 3; ++s)
#pragma unroll
      for (int f = 0; f < 4; ++f)
        af[s][f] = *(const bf16x8*)&lds[s * 8192 + offA0[f]];
#pragma unroll
    for (int nf = 0; nf < 4; ++nf) {
      bf16x8 b0 = *(const bf16x8*)&lds[offB0[nf]];
      bf16x8 b1 = *(const bf16x8*)&lds[8192 + offB0[nf]];
      bf16x8 b2 = *(const bf16x8*)&lds[16384 + offB0[nf]];
#pragma unroll
      for (int mf = 0; mf < 4; ++mf)
        acc[mf][nf] = __builtin_amdgcn_mfma_f32_16x16x32_bf16(
            af[0][mf], b0, acc[mf][nf], 0, 0, 0);
#pragma unroll
      for (int mf = 0; mf < 4; ++mf)
        acc[mf][nf] = __builtin_amdgcn_mfma_f32_16x16x32_bf16(
            af[0][mf], b1, acc[mf][nf], 0, 0, 0);
#pragma unroll
      for (int mf = 0; mf < 4; ++mf)
        acc[mf][nf] = __builtin_amdgcn_mfma_f32_16x16x32_bf16(
            af[1][mf], b0, acc[mf][nf], 0, 0, 0);
#pragma unroll
      for (int mf = 0; mf < 4; ++mf)
        acc[mf][nf] = __builtin_amdgcn_mfma_f32_16x16x32_bf16(
            af[0][mf], b2, acc[mf][nf], 0, 0, 0);
#pragma unroll
      for (int mf = 0; mf < 4; ++mf)
        acc[mf][nf] = __builtin_amdgcn_mfma_f32_16x16x32_bf16(
            af[1][mf], b1, acc[mf][nf], 0, 0, 0);
#pragma unroll
      for (int mf = 0; mf < 4; ++mf)
        acc[mf][nf] = __builtin_amdgcn_mfma_f32_16x16x32_bf16(
            af[2][mf], b0, acc[mf][nf], 0, 0, 0);
#pragma unroll
      for (int mf = 0; mf < 4; ++mf)
        acc[mf][nf] = __builtin_amdgcn_mfma_f32_16x16x32_bf16(
            af[1][mf], b2, acc[mf][nf], 0, 0, 0);
#pragma unroll
      for (int mf = 0; mf < 4; ++mf)
        acc[mf][nf] = __builtin_amdgcn_mfma_f32_16x16x32_bf16(
            af[2][mf], b1, acc[mf][nf], 0, 0, 0);
    }
    __syncthreads();
  }

  // ---- epilogue: bias (+leaky), store fp32 ----
#pragma unroll
  for (int nf = 0; nf < 4; ++nf) {
    int col = n0 + ((w >> 1) << 6) + (nf << 4) + l15;
    float bz = bias[col];
#pragma unroll
    for (int mf = 0; mf < 4; ++mf) {
#pragma unroll
      for (int r = 0; r < 4; ++r) {
        int row = m0 + ((w & 1) << 6) + (mf << 4) + (q << 2) + r;
        float x = acc[mf][nf][r] + bz;
        if (LEAKY) x = (x > 0.f) ? x : 0.1f * x;
        C[(long long)row * 1024 + col] = x;
      }
    }
  }
}

// ---------------------------------------------------------------------------
// Batched NT GEMM for scores (fp32, 128x128 tile, 8x8 microtile, dbuf LDS).
// C = A[M,K] * B^T + rowAdd[m] + scal. grid = (N/128, M/128, batch).
// ---------------------------------------------------------------------------
__global__ __launch_bounds__(256) void gemmnt_kernel(
    const float* __restrict__ A, int lda, long long sA,
    const float* __restrict__ B, int ldb, long long sB,
    float* __restrict__ C, int ldc, long long sC,
    const float* __restrict__ rowAdd, long long sRow,
    const float* __restrict__ scal, int K) {
  const int bz = blockIdx.z;
  A += (long long)bz * sA;
  B += (long long)bz * sB;
  C += (long long)bz * sC;
  const int m0 = blockIdx.y * 128;
  const int n0 = blockIdx.x * 128;
  __shared__ __align__(16) float As[2][8][128];
  __shared__ __align__(16) float Bs[2][8][128];
  const int t = threadIdx.x;
  const int tx = t & 15, ty = t >> 4;
  const int arow = t >> 1, ak = (t & 1) * 4;
  const int bn_t = t >> 1, bk_t = (t & 1) * 4;

  float acc[8][8];
#pragma unroll
  for (int i = 0; i < 8; ++i)
#pragma unroll
    for (int j = 0; j < 8; ++j) acc[i][j] = 0.f;

  {
    float4 av = *(const float4*)(A + (long long)(m0 + arow) * lda + ak);
    float4 bv = *(const float4*)(B + (long long)(n0 + bn_t) * ldb + bk_t);
    As[0][ak + 0][arow] = av.x;
    As[0][ak + 1][arow] = av.y;
    As[0][ak + 2][arow] = av.z;
    As[0][ak + 3][arow] = av.w;
    Bs[0][bk_t + 0][bn_t] = bv.x;
    Bs[0][bk_t + 1][bn_t] = bv.y;
    Bs[0][bk_t + 2][bn_t] = bv.z;
    Bs[0][bk_t + 3][bn_t] = bv.w;
  }
  __syncthreads();

  int cur = 0;
  for (int k0 = 0; k0 < K; k0 += 8) {
    float4 av, bv;
    const bool more = (k0 + 8) < K;
    if (more) {
      av = *(const float4*)(A + (long long)(m0 + arow) * lda + (k0 + 8 + ak));
      bv = *(const float4*)(B + (long long)(n0 + bn_t) * ldb + (k0 + 8 + bk_t));
    }
#pragma unroll
    for (int k = 0; k < 8; ++k) {
      float4 a0 = *(const float4*)&As[cur][k][ty * 4];
      float4 a1 = *(const float4*)&As[cur][k][64 + ty * 4];
      float4 b0 = *(const float4*)&Bs[cur][k][tx * 4];
      float4 b1 = *(const float4*)&Bs[cur][k][64 + tx * 4];
      float a[8] = {a0.x, a0.y, a0.z, a0.w, a1.x, a1.y, a1.z, a1.w};
      float bb[8] = {b0.x, b0.y, b0.z, b0.w, b1.x, b1.y, b1.z, b1.w};
#pragma unroll
      for (int i = 0; i < 8; ++i)
#pragma unroll
        for (int j = 0; j < 8; ++j) acc[i][j] = fmaf(a[i], bb[j], acc[i][j]);
    }
    if (more) {
      const int nxt = cur ^ 1;
      As[nxt][ak + 0][arow] = av.x;
      As[nxt][ak + 1][arow] = av.y;
      As[nxt][ak + 2][arow] = av.z;
      As[nxt][ak + 3][arow] = av.w;
      Bs[nxt][bk_t + 0][bn_t] = bv.x;
      Bs[nxt][bk_t + 1][bn_t] = bv.y;
      Bs[nxt][bk_t + 2][bn_t] = bv.z;
      Bs[nxt][bk_t + 3][bn_t] = bv.w;
    }
    __syncthreads();
    cur ^= 1;
  }

  const float sc_add = scal[0];
#pragma unroll
  for (int ih = 0; ih < 2; ++ih) {
#pragma unroll
    for (int ii = 0; ii < 4; ++ii) {
      int row = m0 + ih * 64 + ty * 4 + ii;
      float radd = sc_add + rowAdd[(long long)bz * sRow + row];
#pragma unroll
      for (int jh = 0; jh < 2; ++jh) {
        int col = n0 + jh * 64 + tx * 4;
        float4 v = make_float4(acc[ih * 4 + ii][jh * 4 + 0] + radd,
                               acc[ih * 4 + ii][jh * 4 + 1] + radd,
                               acc[ih * 4 + ii][jh * 4 + 2] + radd,
                               acc[ih * 4 + ii][jh * 4 + 3] + radd);
        *(float4*)(C + (long long)row * ldc + col) = v;
      }
    }
  }
}

// ---------------------------------------------------------------------------
// tmpb[i] = dot(lefts[i,:], Wbil[0:H, H]) + Wbil[H,H].  One wave per row.
// ---------------------------------------------------------------------------
__global__ __launch_bounds__(64) void colvec_kernel(
    const float* __restrict__ lefts, const float* __restrict__ bcol,
    const float* __restrict__ corner, float* __restrict__ tmpb) {
  int row = blockIdx.x;
  int lane = threadIdx.x;
  const float* a = lefts + (long long)row * Hh;
  float s = 0.f;
#pragma unroll
  for (int h = lane; h < Hh; h += 64) s = fmaf(a[h], bcol[h], s);
#pragma unroll
  for (int off = 32; off > 0; off >>= 1) s += __shfl_down(s, off, 64);
  if (lane == 0) tmpb[row] = s + corner[0];
}

// ---------------------------------------------------------------------------
// CKY + backtrack (round-3 kernel, known-good). One block per batch, 1024
// threads. Chart in LDS, packed triangular diag-major; adaptive m-split
// (G,T) = (4,256)/(8,128)/(16,64); ascending-g strict-> combine preserves
// jnp.argmax first-max semantics; LDS backtrack.
// ---------------------------------------------------------------------------
__global__ __launch_bounds__(1024) void cky_kernel(
    const float* __restrict__ scores,  // [64][256][256]
    uint8_t* __restrict__ Sws,         // [64][32896] packed triangular
    int* __restrict__ out)             // [2][64][256] int32
{
  const int b = blockIdx.x;
  const int t = threadIdx.x;
  const int n = Ss;
  const float* sc = scores + (long long)b * n * n;
  uint8_t* SP = Sws + (long long)b * 32896;

  __shared__ float Dch[32896];
  __shared__ float pv[1024];
  __shared__ uint8_t pmv[1024];
  __shared__ int stk[256];

  if (t < n) {
    out[b * n + t] = 0;
    out[Bb * n + b * n + t] = 0;
    Dch[t] = 0.f;
  }
  __syncthreads();

  int offw = n;  // off(1)
  for (int w = 1; w < n; ++w) {
    const int nv = n - w;
    const int lgT = (nv > 128) ? 8 : ((nv > 64) ? 7 : 6);
    const int T = 1 << lgT;
    const int G = 1024 >> lgT;
    const int g = t >> lgT;
    const int u = t & (T - 1);

    float scv = 0.f;
    if (t < nv) scv = sc[t * (n + 1) + w];

    const int wG = (w + G - 1) >> (10 - lgT);
    const int ml = g * wG;
    const int mh = (w < ml + wG) ? w : (ml + wG);
    float best = -3.0e38f;
    int bmv = 0;
    if (u < nv && ml < mh) {
      int al = ml * n - ((ml * (ml - 1)) >> 1) + u;
      const int kr = w - 1 - ml;
      int ar = kr * n - ((kr * (kr - 1)) >> 1) + u + ml + 1;
      int dl = n - ml;
      int dr = n - w + ml + 1;
#pragma unroll 4
      for (int m = ml; m < mh; ++m) {
        float c = Dch[al] + Dch[ar];
        if (c > best) {
          best = c;
          bmv = m;
        }
        al += dl;
        ar -= dr;
        --dl;
        ++dr;
      }
    }
    pv[t] = best;
    pmv[t] = (uint8_t)bmv;
    __syncthreads();

    if (t < nv) {
      float bb = pv[t];
      int bm = pmv[t];
      for (int g2 = 1; g2 < G; ++g2) {
        float v = pv[g2 * T + t];
        if (v > bb) {
          bb = v;
          bm = pmv[g2 * T + t];
        }
      }
      Dch[offw + t] = scv + bb;
      SP[offw + t] = (uint8_t)bm;
    }
    __syncthreads();
    offw += nv;
  }

  uint8_t* spl = (uint8_t*)Dch;
  for (int idx = t; idx < 32896; idx += 1024) spl[idx] = SP[idx];
  __syncthreads();
  if (t == 0) {
    int top = 0;
    stk[top++] = (0 << 16) | (n - 1);
    int cnt = 0;
    for (int step = 0; step < n - 1; ++step) {
      if (top > 0) {
        int ij = stk[--top];
        int ii = ij >> 16, jj = ij & 0xffff;
        out[b * n + cnt] = ii;
        out[Bb * n + b * n + cnt] = jj;
        ++cnt;
        int k = jj - ii;
        int s = ii + (int)spl[k * n - ((k * (k - 1)) >> 1) + ii];
        stk[top] = (ii << 16) | s;
        if (s > ii) ++top;
        stk[top] = ((s + 1) << 16) | jj;
        if (jj > s + 1) ++top;
      }
    }
  }
}

// ---------------------------------------------------------------------------
// Launch
// ---------------------------------------------------------------------------
extern "C" void kernel_launch(void* const* d_in, const int* in_sizes, int n_in,
                              void* d_out, int out_size, void* d_ws,
                              size_t ws_size, hipStream_t stream) {
  const float* X = (const float*)d_in[0];     // [64,256,1024]
  const float* Wl = (const float*)d_in[2];    // [1024,1024]
  const float* bl = (const float*)d_in[3];    // [1024]
  const float* Wr = (const float*)d_in[4];
  const float* br = (const float*)d_in[5];
  const float* Wbil = (const float*)d_in[6];  // [1025,1025]
  const float* bbil = (const float*)d_in[7];  // scalar
  int* out = (int*)d_out;

  // workspace layout
  float* ws = (float*)d_ws;
  float* lefts = ws;                          // 16777216 f
  float* rights = lefts + 16777216;           // 16777216 f
  float* tmpA = rights + 16777216;            // 16777216 f
  float* scoresP = tmpA + 16777216;           // 4194304 f
  float* tmpb = scoresP + 4194304;            // 16384 f
  float* browp = tmpb + 16384;                // 1024 f
  float* bcolp = browp + 1024;                // 1024 f
  float* cornerp = bcolp + 1024;              // 4 f
  unsigned short* Wlt = (unsigned short*)(cornerp + 4);  // 3 x 1M bf16
  unsigned short* Wrt = Wlt + 3 * 1048576;               // 3 x 1M bf16
  unsigned short* Wct = Wrt + 3 * 1048576;               // 3 x 1M bf16
  uint8_t* SPp = (uint8_t*)(Wct + 3 * 1048576);          // 64x32896 u8

  // weight splits (+ Wbil bias vectors)
  splitw_kernel<<<dim3(4096), 256, 0, stream>>>(Wl, 1024, Wlt);
  splitw_kernel<<<dim3(4096), 256, 0, stream>>>(Wr, 1024, Wrt);
  splitw_kernel<<<dim3(4096), 256, 0, stream>>>(Wbil, 1025, Wct);
  bilvec_kernel<<<dim3(4), 256, 0, stream>>>(Wbil, browp, bcolp, cornerp);

  dim3 gg(8, 128);  // N/128, M/128
  gemm_mfma_kernel<true><<<gg, 256, 0, stream>>>(X, Wlt, lefts, bl);
  gemm_mfma_kernel<true><<<gg, 256, 0, stream>>>(X, Wrt, rights, br);

  colvec_kernel<<<dim3(16384), 64, 0, stream>>>(lefts, bcolp, cornerp, tmpb);

  gemm_mfma_kernel<false><<<gg, 256, 0, stream>>>(lefts, Wct, tmpA, browp);

  dim3 g3(Ss / 128, Ss / 128, Bb);  // (2,2,64)
  gemmnt_kernel<<<g3, 256, 0, stream>>>(
      tmpA, Hh, (long long)Ss * Hh, rights, Hh, (long long)Ss * Hh, scoresP,
      Ss, (long long)Ss * Ss, tmpb, (long long)Ss, bbil, Hh);

  cky_kernel<<<dim3(Bb), dim3(1024), 0, stream>>>(scoresP, SPp, out);
}